// Round 4
// baseline (74.049 us; speedup 1.0000x reference)
//
#include <hip/hip_runtime.h>

// out[b,u] = sum_d x[b,d] * emb[idx[b],d,u]    B=256, D=1024, U=1024, C=64, fp32
//
// Contiguous-stream variant: grid = (64 classes) x (8 d-chunks of 128).
// Each block streams emb[c, d0:d0+128, 0:1024] = 512 KB FULLY CONTIGUOUS
// (16 KB per dg iteration), accumulates per-thread float4 partials over its
// d-chunk for up to MC examples, then unsafeAtomicAdd's into out (out zeroed
// by hipMemsetAsync on the stream each call; each (b,u) gets exactly 8 adds).
//   - 256 threads; thread t owns u = [4t, 4t+4) for ALL d in the chunk
//   - x chunk rows (12 x 128 floats = 6 KB) staged in LDS, float4 broadcast
//   - wave-uniform mc guards skip dead FMA/LDS work for small classes

#define B_N 256
#define D_N 1024
#define U_N 1024
#define C_N 64
#define MC  12
#define TPB 256
#define DC_N 8
#define DCHUNK (D_N / DC_N)   // 128

__device__ __forceinline__ void fma4(float4& a, const float4& e, float s) {
    a.x = fmaf(e.x, s, a.x);
    a.y = fmaf(e.y, s, a.y);
    a.z = fmaf(e.z, s, a.z);
    a.w = fmaf(e.w, s, a.w);
}

__device__ __forceinline__ void atom_add_f(float* p, float v) {
#if defined(__AMDGCN__)
    unsafeAtomicAdd(p, v);    // native global_atomic_add_f32
#else
    atomicAdd(p, v);
#endif
}

__global__ __launch_bounds__(TPB) void content_dsplit(
    const int* __restrict__ idx,
    const float* __restrict__ x,
    const float* __restrict__ emb,
    float* __restrict__ out)
{
    __shared__ __align__(16) float xs[MC][DCHUNK];  // 6 KB
    __shared__ int bs[B_N];
    __shared__ int cnt;

    const int c   = blockIdx.x;    // class
    const int dc  = blockIdx.y;    // d-chunk
    const int tid = threadIdx.x;   // 0..255

    if (tid == 0) cnt = 0;
    __syncthreads();
    if (idx[tid] == c) {
        bs[atomicAdd(&cnt, 1)] = tid;   // order irrelevant: per-b independent
    }
    __syncthreads();
    const int M = cnt;
    if (M == 0) return;

    const int d0 = dc * DCHUNK;
    const int u0 = tid * 4;

    for (int base = 0; base < M; base += MC) {
        const int mc = min(MC, M - base);

        // ---- stage x chunk rows into LDS (zero-pad unused slots) ----
        #pragma unroll
        for (int j = 0; j < MC; ++j) {
            if (tid < DCHUNK) {
                float v = 0.f;
                if (j < mc) v = x[(size_t)bs[base + j] * D_N + d0 + tid];
                xs[j][tid] = v;
            }
        }
        __syncthreads();

        float4 acc[MC];
        #pragma unroll
        for (int j = 0; j < MC; ++j) acc[j] = make_float4(0.f, 0.f, 0.f, 0.f);

        const bool m4 = (mc > 4);   // block-uniform
        const bool m8 = (mc > 8);

        // ---- main loop: 128 d, 4 rows/iter, 16 KB contiguous per iter ----
        const float* ep = emb + ((size_t)c * D_N + d0) * U_N + u0;
        for (int dg = 0; dg < DCHUNK / 4; ++dg) {   // 32 iterations
            float4 e0 = *(const float4*)(ep);
            float4 e1 = *(const float4*)(ep + U_N);
            float4 e2 = *(const float4*)(ep + 2 * U_N);
            float4 e3 = *(const float4*)(ep + 3 * U_N);
            ep += 4 * U_N;

            #pragma unroll
            for (int j = 0; j < 4; ++j) {
                float4 xv = *(const float4*)&xs[j][dg * 4];  // uniform broadcast
                fma4(acc[j], e0, xv.x); fma4(acc[j], e1, xv.y);
                fma4(acc[j], e2, xv.z); fma4(acc[j], e3, xv.w);
            }
            if (m4) {
                #pragma unroll
                for (int j = 4; j < 8; ++j) {
                    float4 xv = *(const float4*)&xs[j][dg * 4];
                    fma4(acc[j], e0, xv.x); fma4(acc[j], e1, xv.y);
                    fma4(acc[j], e2, xv.z); fma4(acc[j], e3, xv.w);
                }
            }
            if (m8) {
                #pragma unroll
                for (int j = 8; j < MC; ++j) {
                    float4 xv = *(const float4*)&xs[j][dg * 4];
                    fma4(acc[j], e0, xv.x); fma4(acc[j], e1, xv.y);
                    fma4(acc[j], e2, xv.z); fma4(acc[j], e3, xv.w);
                }
            }
        }

        // ---- epilogue: one atomic add per partial-out element ----
        #pragma unroll
        for (int j = 0; j < MC; ++j) {
            if (j < mc) {
                float* op = out + (size_t)bs[base + j] * U_N + u0;
                atom_add_f(op + 0, acc[j].x);
                atom_add_f(op + 1, acc[j].y);
                atom_add_f(op + 2, acc[j].z);
                atom_add_f(op + 3, acc[j].w);
            }
        }
        __syncthreads();   // protect xs restage if another chunk follows
    }
}

extern "C" void kernel_launch(void* const* d_in, const int* in_sizes, int n_in,
                              void* d_out, int out_size, void* d_ws, size_t ws_size,
                              hipStream_t stream) {
    const int*   idx = (const int*)d_in[0];
    const float* x   = (const float*)d_in[1];
    const float* emb = (const float*)d_in[2];
    float*       out = (float*)d_out;

    hipMemsetAsync(out, 0, (size_t)out_size * sizeof(float), stream);

    dim3 grid(C_N, DC_N);   // 64 x 8 = 512 blocks
    dim3 block(TPB);
    content_dsplit<<<grid, block, 0, stream>>>(idx, x, emb, out);
}

// Round 6
// 48.030 us; speedup vs baseline: 1.5417x; 1.5417x over previous
//
#include <hip/hip_runtime.h>

// out[b,u] = sum_d x[b,d] * emb[idx[b],d,u]    B=256, D=1024, U=1024, C=64, fp32
//
// Two-kernel, atomic-free, contiguous-stream version.
// K1: grid (64 classes x 4 d-chunks of 256 rows), 1024 thr = 16 waves.
//     thread: uq=tid&255 -> u0=uq*4 (float4), ds=tid>>8 (0..3) -> d-subslice of
//     64 rows. The 4 waves sharing a d-subslice jointly cover each full 4KB emb
//     row -> DRAM-page-local streaming, each byte read once, nontemporal
//     (bypass L2 allocation). Intra-block 4-way d-reduction in LDS,
//     partial[dc][b][u] written to d_ws with plain stores.
// K2: out[b,u] = sum_dc partial[dc][b][u]  (4MB read, 1MB write, ~2us).
// Fallback: if ws_size < 4MB, run the proven round-2 single-kernel version.

#define B_N 256
#define D_N 1024
#define U_N 1024
#define C_N 64
#define MC  12
#define DC  4
#define DROWS (D_N / DC)      // 256 rows per chunk
#define TPB1 1024

typedef float f32x4 __attribute__((ext_vector_type(4)));

__device__ __forceinline__ void fma4(float4& a, const float4& e, float s) {
    a.x = fmaf(e.x, s, a.x);
    a.y = fmaf(e.y, s, a.y);
    a.z = fmaf(e.z, s, a.z);
    a.w = fmaf(e.w, s, a.w);
}
__device__ __forceinline__ float4 ntload4(const float* p) {
    f32x4 v = __builtin_nontemporal_load((const f32x4*)p);
    return make_float4(v.x, v.y, v.z, v.w);
}

// ---------------- Kernel 1: per-(class, d-chunk) partials ----------------
__global__ __launch_bounds__(TPB1, 4) void content_partial(
    const int* __restrict__ idx,
    const float* __restrict__ x,
    const float* __restrict__ emb,
    float* __restrict__ part)     // [DC][B_N][U_N]
{
    __shared__ __align__(16) float xs[MC][DROWS];   // 12 KB chunk-local x rows
    __shared__ __align__(16) float4 red[4 * 256];   // 16 KB reduction buffer
    __shared__ int bs[B_N];
    __shared__ int cnt;

    const int c   = blockIdx.x;
    const int dc  = blockIdx.y;
    const int tid = threadIdx.x;   // 0..1023
    const int uq  = tid & 255;     // u quarter-index
    const int ds  = tid >> 8;      // 0..3 d-subslice (64 rows each)

    if (tid == 0) cnt = 0;
    __syncthreads();
    if (tid < B_N && idx[tid] == c) {
        bs[atomicAdd(&cnt, 1)] = tid;   // LDS atomic; order irrelevant
    }
    __syncthreads();
    const int M = cnt;
    if (M == 0) return;

    const int u0 = uq * 4;
    const int drow0 = dc * DROWS + ds * (DROWS / 4);   // chunk base + subslice
    const float* ebase = emb + ((size_t)c * D_N + drow0) * U_N + u0;

    for (int base = 0; base < M; base += MC) {
        const int mc = min(MC, M - base);

        // stage chunk-local x rows: j = jj*4 + ds, d-local = uq
        #pragma unroll
        for (int jj = 0; jj < MC / 4; ++jj) {
            const int j = jj * 4 + ds;
            float v = 0.f;
            if (j < mc) v = x[(size_t)bs[base + j] * D_N + dc * DROWS + uq];
            xs[j][uq] = v;
        }
        __syncthreads();

        float4 acc[MC];
        #pragma unroll
        for (int j = 0; j < MC; ++j) acc[j] = make_float4(0.f, 0.f, 0.f, 0.f);

        const bool m4 = (mc > 4);   // block-uniform
        const bool m8 = (mc > 8);

        // main loop: 64 rows per subslice, 4 rows/iter (16 iters).
        // 4 sibling waves cover each full 4KB row -> page-local stream.
        const float* ep = ebase;
        for (int dg = 0; dg < (DROWS / 4) / 4; ++dg) {
            float4 e0 = ntload4(ep);
            float4 e1 = ntload4(ep + U_N);
            float4 e2 = ntload4(ep + 2 * U_N);
            float4 e3 = ntload4(ep + 3 * U_N);
            ep += 4 * U_N;
            const int dl = ds * (DROWS / 4) + dg * 4;   // d-local in chunk

            #pragma unroll
            for (int j = 0; j < 4; ++j) {
                float4 xv = *(const float4*)&xs[j][dl];   // uniform broadcast
                fma4(acc[j], e0, xv.x); fma4(acc[j], e1, xv.y);
                fma4(acc[j], e2, xv.z); fma4(acc[j], e3, xv.w);
            }
            if (m4) {
                #pragma unroll
                for (int j = 4; j < 8; ++j) {
                    float4 xv = *(const float4*)&xs[j][dl];
                    fma4(acc[j], e0, xv.x); fma4(acc[j], e1, xv.y);
                    fma4(acc[j], e2, xv.z); fma4(acc[j], e3, xv.w);
                }
            }
            if (m8) {
                #pragma unroll
                for (int j = 8; j < MC; ++j) {
                    float4 xv = *(const float4*)&xs[j][dl];
                    fma4(acc[j], e0, xv.x); fma4(acc[j], e1, xv.y);
                    fma4(acc[j], e2, xv.z); fma4(acc[j], e3, xv.w);
                }
            }
        }

        // 4-way cross-subslice reduction, plain stores to partials
        #pragma unroll
        for (int j = 0; j < MC; ++j) {
            if (j < mc) {                      // block-uniform
                red[ds * 256 + uq] = acc[j];   // j static: acc stays in regs
                __syncthreads();
                if (ds == 0) {
                    float4 a0 = red[uq];
                    float4 a1 = red[256 + uq];
                    float4 a2 = red[512 + uq];
                    float4 a3 = red[768 + uq];
                    float4 s;
                    s.x = (a0.x + a1.x) + (a2.x + a3.x);
                    s.y = (a0.y + a1.y) + (a2.y + a3.y);
                    s.z = (a0.z + a1.z) + (a2.z + a3.z);
                    s.w = (a0.w + a1.w) + (a2.w + a3.w);
                    *(float4*)(part + ((size_t)dc * B_N + bs[base + j]) * U_N + u0) = s;
                }
                __syncthreads();
            }
        }
        __syncthreads();   // protect xs restage if another pass follows
    }
}

// ---------------- Kernel 2: sum the 4 d-chunk partials ----------------
__global__ __launch_bounds__(256) void content_reduce(
    const float* __restrict__ part, float* __restrict__ out)
{
    const int i = blockIdx.x * 256 + threadIdx.x;       // float4 index, 0..65535
    const f32x4* p = (const f32x4*)part;
    f32x4 a = __builtin_nontemporal_load(p + i);
    f32x4 b = __builtin_nontemporal_load(p + 65536 + i);
    f32x4 c = __builtin_nontemporal_load(p + 131072 + i);
    f32x4 d = __builtin_nontemporal_load(p + 196608 + i);
    f32x4 s = (a + b) + (c + d);
    ((f32x4*)out)[i] = s;
}

// ---------------- Fallback: proven round-2 single kernel ----------------
#define NW_FB 16
__global__ __launch_bounds__(1024, 4) void content_fb(
    const int* __restrict__ idx, const float* __restrict__ x,
    const float* __restrict__ emb, float* __restrict__ out)
{
    __shared__ __align__(16) float smem[MC * D_N];
    __shared__ int bs[B_N];
    __shared__ int cnt;
    const int c = blockIdx.x, ut = blockIdx.y, tid = threadIdx.x;
    const int wave = tid >> 6, lane = tid & 63;
    if (tid == 0) cnt = 0;
    __syncthreads();
    if (tid < B_N && idx[tid] == c) bs[atomicAdd(&cnt, 1)] = tid;
    __syncthreads();
    const int M = cnt;
    if (M == 0) return;
    const int u0 = ut * 256 + lane * 4;
    const int d0 = wave * (D_N / NW_FB);
    const float* ebase = emb + ((size_t)c * D_N + d0) * U_N + u0;
    for (int base = 0; base < M; base += MC) {
        const int mc = min(MC, M - base);
        #pragma unroll
        for (int j = 0; j < MC; ++j) {
            float v = 0.f;
            if (j < mc) v = x[(size_t)bs[base + j] * D_N + tid];
            smem[j * D_N + tid] = v;
        }
        __syncthreads();
        float4 acc[MC];
        #pragma unroll
        for (int j = 0; j < MC; ++j) acc[j] = make_float4(0.f, 0.f, 0.f, 0.f);
        const bool m4 = (mc > 4), m8 = (mc > 8);
        const float* ep = ebase;
        for (int dg = 0; dg < (D_N / NW_FB) / 4; ++dg) {
            float4 e0 = *(const float4*)(ep);
            float4 e1 = *(const float4*)(ep + U_N);
            float4 e2 = *(const float4*)(ep + 2 * U_N);
            float4 e3 = *(const float4*)(ep + 3 * U_N);
            ep += 4 * U_N;
            const int dx = d0 + dg * 4;
            #pragma unroll
            for (int j = 0; j < 4; ++j) {
                float4 xv = *(const float4*)&smem[j * D_N + dx];
                fma4(acc[j], e0, xv.x); fma4(acc[j], e1, xv.y);
                fma4(acc[j], e2, xv.z); fma4(acc[j], e3, xv.w);
            }
            if (m4) {
                #pragma unroll
                for (int j = 4; j < 8; ++j) {
                    float4 xv = *(const float4*)&smem[j * D_N + dx];
                    fma4(acc[j], e0, xv.x); fma4(acc[j], e1, xv.y);
                    fma4(acc[j], e2, xv.z); fma4(acc[j], e3, xv.w);
                }
            }
            if (m8) {
                #pragma unroll
                for (int j = 8; j < MC; ++j) {
                    float4 xv = *(const float4*)&smem[j * D_N + dx];
                    fma4(acc[j], e0, xv.x); fma4(acc[j], e1, xv.y);
                    fma4(acc[j], e2, xv.z); fma4(acc[j], e3, xv.w);
                }
            }
        }
        __syncthreads();
        float4* red = (float4*)smem;
        #pragma unroll
        for (int j = 0; j < MC; ++j) {
            if (j < mc) {
                red[tid] = acc[j];
                __syncthreads();
                if (tid < 64) {
                    float4 s = red[tid];
                    #pragma unroll
                    for (int w = 1; w < NW_FB; ++w) {
                        float4 a = red[w * 64 + tid];
                        s.x += a.x; s.y += a.y; s.z += a.z; s.w += a.w;
                    }
                    *(float4*)(out + (size_t)bs[base + j] * U_N + ut * 256 + tid * 4) = s;
                }
                __syncthreads();
            }
        }
        __syncthreads();
    }
}

extern "C" void kernel_launch(void* const* d_in, const int* in_sizes, int n_in,
                              void* d_out, int out_size, void* d_ws, size_t ws_size,
                              hipStream_t stream) {
    const int*   idx = (const int*)d_in[0];
    const float* x   = (const float*)d_in[1];
    const float* emb = (const float*)d_in[2];
    float*       out = (float*)d_out;

    const size_t need = (size_t)DC * B_N * U_N * sizeof(float);   // 4 MB
    if (ws_size >= need) {
        float* part = (float*)d_ws;
        dim3 g1(C_N, DC);                 // 64 x 4 = 256 blocks
        content_partial<<<g1, TPB1, 0, stream>>>(idx, x, emb, part);
        content_reduce<<<256, 256, 0, stream>>>(part, out);
    } else {
        dim3 g(C_N, U_N / 256);
        content_fb<<<g, 1024, 0, stream>>>(idx, x, emb, out);
    }
}

// Round 7
// 44.722 us; speedup vs baseline: 1.6558x; 1.0740x over previous
//
#include <hip/hip_runtime.h>

// out[b,u] = sum_d x[b,d] * emb[idx[b],d,u]    B=256, D=1024, U=1024, C=64, fp32
//
// Round-2 structure (proven 5.8 TB/s stream) + parallelized epilogue.
// Grid: (64 classes) x (4 u-tiles of 256). Block: 1024 threads = 16 waves,
// 1 block/CU. Wave w owns d-slice [w*64, w*64+64); lane owns 4 consecutive u.
//   - block scans content_idx, builds its class's example list (skip if empty)
//   - x rows staged in LDS (float4), broadcast-read per 4-d group
//   - emb slice (1 MB) streamed once as float4 (1 KB/wave-instruction)
//   - epilogue: 3 phases x 4 examples; stage 64 KB of accs in one shot, then
//     4 waves (one per example, different SIMDs) do the 16-way reduction and
//     1 KB-contiguous stores. <=6 barriers instead of 24, reduce 4x parallel.

#define B_N 256
#define D_N 1024
#define U_N 1024
#define C_N 64
#define MC  12
#define NW  16
#define TPB 1024

__device__ __forceinline__ void fma4(float4& a, const float4& e, float s) {
    a.x = fmaf(e.x, s, a.x);
    a.y = fmaf(e.y, s, a.y);
    a.z = fmaf(e.z, s, a.z);
    a.w = fmaf(e.w, s, a.w);
}

__global__ __launch_bounds__(TPB, 4) void content_gather_gemv(
    const int* __restrict__ idx,
    const float* __restrict__ x,
    const float* __restrict__ emb,
    float* __restrict__ out)
{
    // 64 KB: xs ([MC][D_N] = 48 KB) during stream; red ([4][16][64] float4
    // = 64 KB) during epilogue (xs dead by then; barrier-separated).
    __shared__ __align__(16) float smem[16 * 1024];
    __shared__ int bs[B_N];
    __shared__ int cnt;

    const int c    = blockIdx.x;     // class
    const int ut   = blockIdx.y;     // u-tile (256 u)
    const int tid  = threadIdx.x;    // 0..1023
    const int wave = tid >> 6;       // 0..15 -> d-slice of 64
    const int lane = tid & 63;       // -> 4 u's

    if (tid == 0) cnt = 0;
    __syncthreads();
    if (tid < B_N && idx[tid] == c) {
        bs[atomicAdd(&cnt, 1)] = tid;   // order irrelevant: per-b independent
    }
    __syncthreads();
    const int M = cnt;
    if (M == 0) return;

    const int u0 = ut * 256 + lane * 4;
    const int d0 = wave * (D_N / NW);           // 64 d per wave
    const float* ebase = emb + ((size_t)c * D_N + d0) * U_N + u0;

    for (int base = 0; base < M; base += MC) {
        const int mc = min(MC, M - base);

        // ---- stage x rows into LDS, float4 (zero-pad unused slots) ----
        {
            const int jr = tid >> 8;    // 0..3
            const int dq = tid & 255;   // float4 slot within row
            #pragma unroll
            for (int jj = 0; jj < MC / 4; ++jj) {
                const int j = jj * 4 + jr;
                float4 v = make_float4(0.f, 0.f, 0.f, 0.f);
                if (j < mc) v = *(const float4*)(x + (size_t)bs[base + j] * D_N + dq * 4);
                *(float4*)&smem[j * D_N + dq * 4] = v;
            }
        }
        __syncthreads();

        float4 acc[MC];
        #pragma unroll
        for (int j = 0; j < MC; ++j) acc[j] = make_float4(0.f, 0.f, 0.f, 0.f);

        const bool m4 = (mc > 4);   // block-uniform
        const bool m8 = (mc > 8);

        // ---- main loop: 64 d per wave, 4 rows per iteration (16 iters) ----
        const float* ep = ebase;
        for (int dg = 0; dg < (D_N / NW) / 4; ++dg) {
            float4 e0 = *(const float4*)(ep);
            float4 e1 = *(const float4*)(ep + U_N);
            float4 e2 = *(const float4*)(ep + 2 * U_N);
            float4 e3 = *(const float4*)(ep + 3 * U_N);
            ep += 4 * U_N;
            const int dx = d0 + dg * 4;

            #pragma unroll
            for (int j = 0; j < 4; ++j) {
                float4 xv = *(const float4*)&smem[j * D_N + dx];  // broadcast
                fma4(acc[j], e0, xv.x); fma4(acc[j], e1, xv.y);
                fma4(acc[j], e2, xv.z); fma4(acc[j], e3, xv.w);
            }
            if (m4) {
                #pragma unroll
                for (int j = 4; j < 8; ++j) {
                    float4 xv = *(const float4*)&smem[j * D_N + dx];
                    fma4(acc[j], e0, xv.x); fma4(acc[j], e1, xv.y);
                    fma4(acc[j], e2, xv.z); fma4(acc[j], e3, xv.w);
                }
            }
            if (m8) {
                #pragma unroll
                for (int j = 8; j < MC; ++j) {
                    float4 xv = *(const float4*)&smem[j * D_N + dx];
                    fma4(acc[j], e0, xv.x); fma4(acc[j], e1, xv.y);
                    fma4(acc[j], e2, xv.z); fma4(acc[j], e3, xv.w);
                }
            }
        }

        __syncthreads();   // all waves done reading xs; smem reusable

        // ---- phased epilogue: 4 j's per phase, all-wave stage, 4-wave reduce ----
        float4* red = (float4*)smem;   // [jj][wave][lane] = [4][16][64] float4
        #pragma unroll
        for (int ph = 0; ph < MC / 4; ++ph) {
            const int jbase = ph * 4;
            if (jbase < mc) {          // block-uniform -> barriers legal inside
                #pragma unroll
                for (int jj = 0; jj < 4; ++jj) {
                    if (jbase + jj < mc)
                        red[(jj * NW + wave) * 64 + lane] = acc[jbase + jj];
                }
                __syncthreads();
                const int jl  = tid >> 8;    // 0..3 -> which j
                const int sub = tid & 255;
                const int j   = jbase + jl;
                if (sub < 64 && j < mc) {    // waves 0,4,8,12 (different SIMDs)
                    float4 s = red[(jl * NW) * 64 + sub];
                    #pragma unroll
                    for (int w = 1; w < NW; ++w) {
                        float4 a = red[(jl * NW + w) * 64 + sub];
                        s.x += a.x; s.y += a.y; s.z += a.z; s.w += a.w;
                    }
                    *(float4*)(out + (size_t)bs[base + j] * U_N + ut * 256 + sub * 4) = s;
                }
                __syncthreads();
            }
        }
        __syncthreads();   // protect xs restage if another chunk follows
    }
}

extern "C" void kernel_launch(void* const* d_in, const int* in_sizes, int n_in,
                              void* d_out, int out_size, void* d_ws, size_t ws_size,
                              hipStream_t stream) {
    const int*   idx = (const int*)d_in[0];
    const float* x   = (const float*)d_in[1];
    const float* emb = (const float*)d_in[2];
    float*       out = (float*)d_out;

    dim3 grid(C_N, U_N / 256);   // 64 x 4 = 256 blocks, 1 per CU
    dim3 block(TPB);
    content_gather_gemv<<<grid, block, 0, stream>>>(idx, x, emb, out);
}